// Round 4
// baseline (152.699 us; speedup 1.0000x reference)
//
#include <hip/hip_runtime.h>
#include <stdint.h>

typedef unsigned long long u64;

#define NN 32
#define CC 256
#define HH 28
#define WW 28
#define PP 784          // H*W
#define NHW 25088       // N*H*W
#define WPO 36          // 9 taps * 4 u64 words per output channel

// ---------------------------------------------------------------------------
// prep: coalesced pack_x (lane = pixel) + pack both weight tensors + zero stats
// grid 2176 x 64 threads: bx<1664 -> pack_x unit (n,g,ptile); else pack_w (which,o)
// ---------------------------------------------------------------------------
__global__ __launch_bounds__(64) void prep(const float* __restrict__ x,
        const float* __restrict__ w1, const float* __restrict__ w2,
        u64* __restrict__ xp, u64* __restrict__ wp1, u64* __restrict__ wp2,
        int* s1i, u64* s1q, double* s2s, double* s2q) {
    int bx = blockIdx.x, lane = threadIdx.x;
    if (bx < 1664) {                     // 32 n * 4 g * 13 ptiles
        int n = bx / 52, rem = bx % 52, g = rem / 13, pt = rem % 13;
        int p = pt * 64 + lane;
        if (p < PP) {
            const float* base = x + ((size_t)n * CC + g * 64) * PP + p;
            u64 w = 0;
#pragma unroll 8
            for (int cb = 0; cb < 64; ++cb)
                if (base[(size_t)cb * PP] > 0.0f) w |= (1ull << cb);
            xp[((size_t)n * PP + p) * 4 + g] = w;
        }
    } else {
        int u = bx - 1664, which = u >> 8, o = u & 255;
        if (u < 4) {                     // fold in stats zeroing
            s1i[u * 64 + lane] = 0; s1q[u * 64 + lane] = 0ull;
            s2s[u * 64 + lane] = 0.0; s2q[u * 64 + lane] = 0.0;
        }
        const float* w = which ? w2 : w1;
        u64* wp = which ? wp2 : wp1;
#pragma unroll
        for (int cg = 0; cg < 4; ++cg)
            for (int tap = 0; tap < 9; ++tap) {
                u64 m = __ballot(w[((size_t)o * CC + cg * 64 + lane) * 9 + tap] > 0.0f);
                if (lane == 0) wp[(size_t)o * WPO + tap * 4 + cg] = m;
            }
    }
}

// ---------------------------------------------------------------------------
// binconv: XNOR-popcount 3x3 conv. grid (7 rowtiles, 4 oblocks, 32 n), 256 thr.
// Block covers 4 output rows (r0..r0+3) x all 28 cols x 64 channels.
// Wave wid: half h = wid&1 (input cols 13h..13h+14, outputs 14h..14h+13),
//           row-pair rp = wid>>1 (output rows rA=r0+2rp, rA+1).
// Weights: 36 u64 in registers (amdgpu_waves_per_eu(3,3) pins budget to 170).
// Per input column: 8 broadcast ds_read_b128 (4 rows) feed 18 POP4 for 2 rows.
// Transposed-FIR: 3 rotating int accumulators per row, zero-init, uniform
// emit guards (e >= emin) -- no peel code.
// MODE 0: exact int stats of v (for BN1). MODE 1: f64 stats of (v + x) with
// x staged coalesced into LDS [64][113] (odd stride = conflict-free).
// ---------------------------------------------------------------------------

#define POPW(acc, T, wb) acc = (int)__popcll((T) ^ wreg[wb]) + acc;
#define POP4S(acc, T, WB) { POPW(acc, T##0, (WB)+0) POPW(acc, T##1, (WB)+1) \
                            POPW(acc, T##2, (WB)+2) POPW(acc, T##3, (WB)+3) }

#define LOADROW(T, lr, ccc) { \
    ulonglong2 u0 = *(const ulonglong2*)&lin[lr][ccc][0]; \
    ulonglong2 u1 = *(const ulonglong2*)&lin[lr][ccc][2]; \
    T##0 = u0.x; T##1 = u0.y; T##2 = u1.x; T##3 = u1.y; }

#define COLBODY2(ccc, PA,CA,NA, PB,CB,NB) { \
    u64 t00,t01,t02,t03, t10,t11,t12,t13, t20,t21,t22,t23, t30,t31,t32,t33; \
    LOADROW(t1, lw+1, ccc) LOADROW(t2, lw+2, ccc) \
    if (rtopA) { LOADROW(t0, lw, ccc) } \
    if (rbotB) { LOADROW(t3, lw+3, ccc) } \
    if (rtopA) { POP4S(NA, t0, 0) POP4S(CA, t0, 4) POP4S(PA, t0, 8) } \
    POP4S(NA, t1, 12) POP4S(CA, t1, 16) POP4S(PA, t1, 20) \
    POP4S(NB, t1, 0)  POP4S(CB, t1, 4)  POP4S(PB, t1, 8)  \
    POP4S(NA, t2, 24) POP4S(CA, t2, 28) POP4S(PA, t2, 32) \
    POP4S(NB, t2, 12) POP4S(CB, t2, 16) POP4S(PB, t2, 20) \
    if (rbotB) { POP4S(NB, t3, 24) POP4S(CB, t3, 28) POP4S(PB, t3, 32) } }

#define EMIT2(e, AA, AB) { \
    int nc = ((e) == 0 || (e) == 27) ? 2 : 3; \
    int dA = kA * nc - 2 * (AA); int dB = kB * nc - 2 * (AB); \
    vrowA[(size_t)(e) * CC] = (short)dA; vrowB[(size_t)(e) * CC] = (short)dB; \
    if (MODE == 0) { tsi += dA + dB; tqi += dA * dA + dB * dB; } \
    else { float uA = (float)dA + xt[xoffA + (e)]; \
           float uB = (float)dB + xt[xoffA + 28 + (e)]; \
           ts += (double)uA + (double)uB; \
           tq += (double)uA * uA + (double)uB * uB; } }

template<int MODE>
__global__ __attribute__((amdgpu_flat_work_group_size(256, 256), amdgpu_waves_per_eu(3, 3)))
void binconv(const u64* __restrict__ xp, const u64* __restrict__ wp,
             short* __restrict__ vout, const float* __restrict__ xres,
             int* __restrict__ s_i, u64* __restrict__ s_q,
             double* __restrict__ s2s, double* __restrict__ s2q)
{
    __shared__ u64 lin[6][28][4];                     // rows r0-1 .. r0+4
    __shared__ float xt[(MODE == 1) ? (64 * 113) : 1]; // residual tile, odd stride
    __shared__ int ris[(MODE == 0) ? 256 : 1], riq[(MODE == 0) ? 256 : 1];
    __shared__ double rds[(MODE == 1) ? 256 : 1], rdq[(MODE == 1) ? 256 : 1];

    int tid = threadIdx.x, lane = tid & 63, wid = tid >> 6;
    int rt = blockIdx.x, ob = blockIdx.y, n = blockIdx.z;
    int r0 = rt * 4;
    int o = ob * 64 + lane;

    // stage 6 input bit-rows (coalesced 16B chunks)
    for (int idx = tid; idx < 6 * 56; idx += 256) {
        int row = idx / 56, off = idx % 56;
        int gr = r0 - 1 + row;
        if (gr >= 0 && gr < HH) {
            ulonglong2 t = *(const ulonglong2*)(xp + ((size_t)n * PP + gr * WW) * 4 + off * 2);
            *(ulonglong2*)((u64*)lin + row * 112 + off * 2) = t;
        }
    }
    // stage residual x tile coalesced (rows r0..r0+3, 64 channels)
    if (MODE == 1) {
        const float* xb = xres + ((size_t)n * CC + ob * 64) * PP + r0 * WW;
        for (int idx = tid; idx < 1792; idx += 256) {
            int f4 = idx % 7, row = (idx / 7) & 3, ch = idx / 28;
            float4 v = *(const float4*)(xb + (size_t)ch * PP + row * WW + f4 * 4);
            float* d = &xt[ch * 113 + row * 28 + f4 * 4];
            d[0] = v.x; d[1] = v.y; d[2] = v.z; d[3] = v.w;
        }
    }

    // weights -> registers (36 u64 = 72 VGPR; budget pinned at 170)
    u64 wreg[36];
    {
        const ulonglong2* wv = (const ulonglong2*)(wp + (size_t)o * WPO);
#pragma unroll
        for (int k = 0; k < 18; ++k) { ulonglong2 t = wv[k]; wreg[2*k] = t.x; wreg[2*k+1] = t.y; }
    }
    __syncthreads();

    const int h = wid & 1, rp = wid >> 1;
    const int lw = rp * 2;                 // lin row of rA-1
    const int rA = r0 + lw;                // output rows rA, rA+1
    const bool rtopA = (rA > 0), rbotB = (rA + 1 < HH - 1);
    const int kA = 256 * (2 + (rtopA ? 1 : 0));
    const int kB = 256 * (2 + (rbotB ? 1 : 0));
    const int c0 = 13 * h, emin = 14 * h;
    const int xoffA = (MODE == 1) ? (lane * 113 + lw * 28) : 0;

    short* vrowA = vout + ((size_t)n * PP + (size_t)rA * WW) * CC + o;
    short* vrowB = vrowA + (size_t)WW * CC;

    int tsi = 0, tqi = 0; double ts = 0.0, tq = 0.0;
    int aA = 0, bA = 0, cA = 0, aB = 0, bB = 0, cB = 0;

#pragma unroll 1
    for (int t = 0; t < 5; ++t) {
        int i0 = c0 + 3 * t;
        COLBODY2(i0,     bA,cA,aA, bB,cB,aB)
        if (i0 - 1 >= emin) { EMIT2(i0 - 1, bA, bB) }
        bA = 0; bB = 0;
        COLBODY2(i0 + 1, cA,aA,bA, cB,aB,bB)
        if (i0 >= emin)     { EMIT2(i0,     cA, cB) }
        cA = 0; cB = 0;
        COLBODY2(i0 + 2, aA,bA,cA, aB,bB,cB)
        if (i0 + 1 >= emin) { EMIT2(i0 + 1, aA, aB) }
        aA = 0; aB = 0;
    }
    if (h == 1) { EMIT2(27, bA, bB) }      // out 27 completed by input col 27

    if (MODE == 0) { ris[wid * 64 + lane] = tsi; riq[wid * 64 + lane] = tqi; }
    else           { rds[wid * 64 + lane] = ts;  rdq[wid * 64 + lane] = tq; }
    __syncthreads();
    if (wid == 0) {
        if (MODE == 0) {
            int S = ris[lane] + ris[64 + lane] + ris[128 + lane] + ris[192 + lane];
            int Q = riq[lane] + riq[64 + lane] + riq[128 + lane] + riq[192 + lane];
            atomicAdd(&s_i[o], S);
            atomicAdd(&s_q[o], (u64)(long long)Q);
        } else {
            double S = rds[lane] + rds[64 + lane] + rds[128 + lane] + rds[192 + lane];
            double Q = rdq[lane] + rdq[64 + lane] + rdq[128 + lane] + rdq[192 + lane];
            atomicAdd(&s2s[o], S);
            atomicAdd(&s2q[o], Q);
        }
    }
}

// ---------------------------------------------------------------------------
// repack: sign(BN1(v1)) -> bit-pack for conv2, BN1 inline from exact int stats.
// ---------------------------------------------------------------------------
__global__ __launch_bounds__(256) void repack(const short* __restrict__ v1,
                                              const int* __restrict__ s_i, const u64* __restrict__ s_q,
                                              const float* __restrict__ gamma, const float* __restrict__ beta,
                                              u64* __restrict__ xp2) {
    int pt = blockIdx.x, n = blockIdx.y;
    int tid = threadIdx.x, lane = tid & 63, g = tid >> 6;
    int c = tid;
    double mean = (double)s_i[c] * (1.0 / NHW);
    double msq  = (double)s_q[c] * (1.0 / NHW);
    double var  = msq - mean * mean;
    double istd = 1.0 / sqrt(var + 1e-5);
    double ad   = (double)gamma[c] * istd;
    float a = (float)ad;
    float b = (float)((double)beta[c] - mean * ad);
#pragma unroll
    for (int i = 0; i < 16; ++i) {
        int p = pt * 16 + i;
        int v = v1[((size_t)n * PP + p) * CC + c];
        u64 m = __ballot(fmaf(a, (float)v, b) > 0.0f);
        if (lane == 0) xp2[((size_t)n * PP + p) * 4 + g] = m;
    }
}

// ---------------------------------------------------------------------------
// finalize: out = clip(SC*(v2 + x) + BI, -1, 1); BN2 inline from f64 stats.
// NHWC int16 -> NCHW f32 via LDS transpose.
// ---------------------------------------------------------------------------
__global__ __launch_bounds__(256) void finalize(const short* __restrict__ v2, const float* __restrict__ x,
                                                const double* __restrict__ s2s, const double* __restrict__ s2q,
                                                const float* __restrict__ gamma, const float* __restrict__ beta,
                                                float* __restrict__ out) {
    __shared__ short t[64 * 66];
    __shared__ float scs[64], bis[64];
    int ct = blockIdx.x, pt = blockIdx.y, n = blockIdx.z;
    int p0 = pt * 64, c0 = ct * 64;
    int tid = threadIdx.x;
    if (tid < 64) {
        int c = c0 + tid;
        double mean = s2s[c] * (1.0 / NHW);
        double msq  = s2q[c] * (1.0 / NHW);
        double var  = msq - mean * mean;
        double istd = 1.0 / sqrt(var + 1e-5);
        double ad   = (double)gamma[c] * istd;
        scs[tid] = (float)ad;
        bis[tid] = (float)((double)beta[c] - mean * ad);
    }
    for (int idx = tid; idx < 64 * 64; idx += 256) {
        int i = idx >> 6, j = idx & 63;
        int p = p0 + i;
        if (p < PP) t[i * 66 + j] = v2[((size_t)n * PP + p) * CC + c0 + j];
    }
    __syncthreads();
    int pl = tid & 63;
    int p = p0 + pl;
    if (p < PP) {
        for (int cl = tid >> 6; cl < 64; cl += 4) {
            int c = c0 + cl;
            float val = (float)t[pl * 66 + cl] + x[((size_t)n * CC + c) * PP + p];
            float r = fmaf(scs[cl], val, bis[cl]);
            r = fminf(fmaxf(r, -1.0f), 1.0f);
            out[((size_t)n * CC + c) * PP + p] = r;
        }
    }
}

// ---------------------------------------------------------------------------
extern "C" void kernel_launch(void* const* d_in, const int* in_sizes, int n_in,
                              void* d_out, int out_size, void* d_ws, size_t ws_size,
                              hipStream_t stream) {
    (void)in_sizes; (void)n_in; (void)out_size; (void)ws_size;
    const float* x   = (const float*)d_in[0];
    const float* w1  = (const float*)d_in[1];
    const float* g1  = (const float*)d_in[2];
    const float* b1  = (const float*)d_in[3];
    const float* w2  = (const float*)d_in[4];
    const float* g2  = (const float*)d_in[5];
    const float* b2  = (const float*)d_in[6];
    float* out = (float*)d_out;

    char* ws = (char*)d_ws;
    u64*    xp1 = (u64*)(ws + 0);            //   802816 B
    u64*    xp2 = (u64*)(ws + 802816);       //   802816 B
    u64*    wp1 = (u64*)(ws + 1605632);      //    73728 B
    u64*    wp2 = (u64*)(ws + 1679360);      //    73728 B
    int*    s1i = (int*)(ws + 1753088);      //     1024 B
    u64*    s1q = (u64*)(ws + 1754112);      //     2048 B
    double* s2s = (double*)(ws + 1756160);   //     2048 B
    double* s2q = (double*)(ws + 1758208);   //     2048 B
    short*  v12 = (short*)(ws + 1764352);    // 12845056 B (v1, then reused as v2)

    prep<<<2176, 64, 0, stream>>>(x, w1, w2, xp1, wp1, wp2, s1i, s1q, s2s, s2q);
    binconv<0><<<dim3(7, 4, 32), 256, 0, stream>>>(xp1, wp1, v12, nullptr, s1i, s1q, nullptr, nullptr);
    repack<<<dim3(49, 32), 256, 0, stream>>>(v12, s1i, s1q, g1, b1, xp2);
    binconv<1><<<dim3(7, 4, 32), 256, 0, stream>>>(xp2, wp2, v12, x, nullptr, nullptr, s2s, s2q);
    finalize<<<dim3(4, 13, 32), 256, 0, stream>>>(v12, x, s2s, s2q, g2, b2, out);
}

// Round 5
// 123.722 us; speedup vs baseline: 1.2342x; 1.2342x over previous
//
#include <hip/hip_runtime.h>
#include <stdint.h>

typedef unsigned long long u64;

#define NN 32
#define CC 256
#define HH 28
#define WW 28
#define PP 784          // H*W
#define NHW 25088       // N*H*W
#define WPO 36          // 9 taps * 4 u64 words per output channel

// ---------------------------------------------------------------------------
// prep: coalesced pack_x (lane = pixel) + pack both weight tensors + zero stats
// grid 2176 x 64 threads: bx<1664 -> pack_x unit (n,g,ptile); else pack_w (which,o)
// ---------------------------------------------------------------------------
__global__ __launch_bounds__(64) void prep(const float* __restrict__ x,
        const float* __restrict__ w1, const float* __restrict__ w2,
        u64* __restrict__ xp, u64* __restrict__ wp1, u64* __restrict__ wp2,
        int* s1i, u64* s1q, double* s2s, double* s2q) {
    int bx = blockIdx.x, lane = threadIdx.x;
    if (bx < 1664) {                     // 32 n * 4 g * 13 ptiles
        int n = bx / 52, rem = bx % 52, g = rem / 13, pt = rem % 13;
        int p = pt * 64 + lane;
        if (p < PP) {
            const float* base = x + ((size_t)n * CC + g * 64) * PP + p;
            u64 w = 0;
#pragma unroll 8
            for (int cb = 0; cb < 64; ++cb)
                if (base[(size_t)cb * PP] > 0.0f) w |= (1ull << cb);
            xp[((size_t)n * PP + p) * 4 + g] = w;
        }
    } else {
        int u = bx - 1664, which = u >> 8, o = u & 255;
        if (u < 4) {                     // fold in stats zeroing
            s1i[u * 64 + lane] = 0; s1q[u * 64 + lane] = 0ull;
            s2s[u * 64 + lane] = 0.0; s2q[u * 64 + lane] = 0.0;
        }
        const float* w = which ? w2 : w1;
        u64* wp = which ? wp2 : wp1;
#pragma unroll
        for (int cg = 0; cg < 4; ++cg)
            for (int tap = 0; tap < 9; ++tap) {
                u64 m = __ballot(w[((size_t)o * CC + cg * 64 + lane) * 9 + tap] > 0.0f);
                if (lane == 0) wp[(size_t)o * WPO + tap * 4 + cg] = m;
            }
    }
}

// ---------------------------------------------------------------------------
// binconv: XNOR-popcount 3x3 conv — transposed-FIR accumulator rotation.
// grid (14 rowtiles, 4 oblocks, 32 n) = 1792 blocks (exactly 7/CU), 128 thr.
// Each wave: ONE output row (r = rt*2 + wid), lane = output channel.
// Weights: 36 u64 PINNED in VGPRs via asm (compiler cannot sink/remat).
// Per input column: 6 broadcast ds_read_b128; 9 POP4 into 3 rotating int accs.
// MODE 0: exact int stats of v. MODE 1: f64 stats of (v + residual), residual
// read directly (per-lane rows are contiguous 112B -> L1-resident).
// ---------------------------------------------------------------------------

#define POPW(acc, T, wb) acc = (int)__popcll((T) ^ wreg[wb]) + acc;
#define POP4(acc, T, WB) { POPW(acc, T[0], (WB)+0) POPW(acc, T[1], (WB)+1) \
                           POPW(acc, T[2], (WB)+2) POPW(acc, T[3], (WB)+3) }

#define LOADROW(T, lr, ccc) { \
    ulonglong2 u0 = *(const ulonglong2*)&lin[lr][ccc][0]; \
    ulonglong2 u1 = *(const ulonglong2*)&lin[lr][ccc][2]; \
    T[0] = u0.x; T[1] = u0.y; T[2] = u1.x; T[3] = u1.y; }

// full column: accumulate into P (out cc-1, wcol2), C (out cc, wcol1), N (out cc+1, wcol0)
#define COLBODY(ccc, AP, AC, AN) { \
    u64 t0[4], t1[4], t2[4]; \
    LOADROW(t1, wid + 1, ccc) \
    if (rtop) { LOADROW(t0, wid, ccc) } \
    if (rbot) { LOADROW(t2, wid + 2, ccc) } \
    if (rtop) { POP4(AN, t0, 0)  POP4(AC, t0, 4)  POP4(AP, t0, 8)  } \
    POP4(AN, t1, 12) POP4(AC, t1, 16) POP4(AP, t1, 20) \
    if (rbot) { POP4(AN, t2, 24) POP4(AC, t2, 28) POP4(AP, t2, 32) } }

#define EMIT(emc, A) { \
    int K = ((emc) == 0 || (emc) == 27) ? bb2 : bb3; \
    int dot = K - 2 * (A); \
    *vptr = (short)dot; vptr += CC; \
    if (MODE == 0) { tsi += dot; tqi += dot * dot; } \
    else { float u = (float)dot + resrow[emc]; tsf += u; tqf = fmaf(u, u, tqf); } }

template<int MODE>
__global__ __attribute__((amdgpu_flat_work_group_size(128, 128), amdgpu_waves_per_eu(3, 4)))
void binconv(const u64* __restrict__ xp, const u64* __restrict__ wp,
             short* __restrict__ vout, const float* __restrict__ xres,
             int* __restrict__ s_i, u64* __restrict__ s_q,
             double* __restrict__ s2s, double* __restrict__ s2q)
{
    __shared__ u64 lin[4][28][4];             // global rows r0-1 .. r0+2
    __shared__ double reds[2][64];
    __shared__ double redq[2][64];

    int tid = threadIdx.x, lane = tid & 63, wid = tid >> 6;
    int rt = blockIdx.x, ob = blockIdx.y, n = blockIdx.z;
    int r0 = rt * 2;
    int o = ob * 64 + lane;

    // stage 4 input bit-rows (coalesced 16B chunks)
    for (int idx = tid; idx < 4 * 56; idx += 128) {
        int row = idx / 56, off = idx % 56;
        int gr = r0 - 1 + row;
        if (gr >= 0 && gr < HH) {
            ulonglong2 t = *(const ulonglong2*)(xp + ((size_t)n * PP + gr * WW) * 4 + off * 2);
            *(ulonglong2*)((u64*)lin + row * 112 + off * 2) = t;
        }
    }

    // weights -> registers, then PIN so the compiler cannot sink the loads
    u64 wreg[36];
    {
        const ulonglong2* wv = (const ulonglong2*)(wp + (size_t)o * WPO);
#pragma unroll
        for (int k = 0; k < 18; ++k) { ulonglong2 t = wv[k]; wreg[2*k] = t.x; wreg[2*k+1] = t.y; }
    }
    asm volatile("" : "+v"(wreg[0]), "+v"(wreg[1]), "+v"(wreg[2]), "+v"(wreg[3]),
                      "+v"(wreg[4]), "+v"(wreg[5]), "+v"(wreg[6]), "+v"(wreg[7]),
                      "+v"(wreg[8]), "+v"(wreg[9]), "+v"(wreg[10]), "+v"(wreg[11]),
                      "+v"(wreg[12]), "+v"(wreg[13]), "+v"(wreg[14]), "+v"(wreg[15]),
                      "+v"(wreg[16]), "+v"(wreg[17]));
    asm volatile("" : "+v"(wreg[18]), "+v"(wreg[19]), "+v"(wreg[20]), "+v"(wreg[21]),
                      "+v"(wreg[22]), "+v"(wreg[23]), "+v"(wreg[24]), "+v"(wreg[25]),
                      "+v"(wreg[26]), "+v"(wreg[27]), "+v"(wreg[28]), "+v"(wreg[29]),
                      "+v"(wreg[30]), "+v"(wreg[31]), "+v"(wreg[32]), "+v"(wreg[33]),
                      "+v"(wreg[34]), "+v"(wreg[35]));
    __syncthreads();

    int r = r0 + wid;                         // this wave's output row
    const bool rtop = (r > 0), rbot = (r < HH - 1);
    const int nr = 1 + (int)rtop + (int)rbot;
    const int bb3 = 256 * nr * 3, bb2 = 256 * nr * 2;

    short* vptr = vout + ((size_t)n * PP + (size_t)r * WW) * CC + o;
    const float* resrow = (MODE == 1) ? (xres + ((size_t)n * CC + o) * PP + r * WW) : nullptr;

    int tsi = 0, tqi = 0; float tsf = 0.0f, tqf = 0.0f;
    int a = 0, b = 0, c = 0;

    // peel input col 0: contributes to out0 (wcol1 -> b) and out1 (wcol0 -> c)
    {
        u64 t0[4], t1[4], t2[4];
        LOADROW(t1, wid + 1, 0)
        if (rtop) { LOADROW(t0, wid, 0) }
        if (rbot) { LOADROW(t2, wid + 2, 0) }
        if (rtop) { POP4(c, t0, 0)  POP4(b, t0, 4)  }
        POP4(c, t1, 12) POP4(b, t1, 16)
        if (rbot) { POP4(c, t2, 24) POP4(b, t2, 28) }
    }

#pragma unroll 1
    for (int m = 0; m < 9; ++m) {
        int cc = 3 * m + 1;
        COLBODY(cc,     b, c, a)  EMIT(cc - 1, b)  b = 0;
        COLBODY(cc + 1, c, a, b)  EMIT(cc,     c)  c = 0;
        COLBODY(cc + 2, a, b, c)  EMIT(cc + 1, a)  a = 0;
    }
    EMIT(27, b)                                // out 27 completed by input col 27

    reds[wid][lane] = (MODE == 0) ? (double)tsi : (double)tsf;
    redq[wid][lane] = (MODE == 0) ? (double)tqi : (double)tqf;
    __syncthreads();
    if (wid == 0) {
        double S = reds[0][lane] + reds[1][lane];
        double Q = redq[0][lane] + redq[1][lane];
        if (MODE == 0) {
            atomicAdd(&s_i[o], (int)S);
            atomicAdd(&s_q[o], (u64)(long long)Q);
        } else {
            atomicAdd(&s2s[o], S);
            atomicAdd(&s2q[o], Q);
        }
    }
}

// ---------------------------------------------------------------------------
// repack: sign(BN1(v1)) -> bit-pack for conv2, BN1 inline from exact int stats.
// ---------------------------------------------------------------------------
__global__ __launch_bounds__(256) void repack(const short* __restrict__ v1,
                                              const int* __restrict__ s_i, const u64* __restrict__ s_q,
                                              const float* __restrict__ gamma, const float* __restrict__ beta,
                                              u64* __restrict__ xp2) {
    int pt = blockIdx.x, n = blockIdx.y;
    int tid = threadIdx.x, lane = tid & 63, g = tid >> 6;
    int c = tid;
    double mean = (double)s_i[c] * (1.0 / NHW);
    double msq  = (double)s_q[c] * (1.0 / NHW);
    double var  = msq - mean * mean;
    double istd = 1.0 / sqrt(var + 1e-5);
    double ad   = (double)gamma[c] * istd;
    float a = (float)ad;
    float b = (float)((double)beta[c] - mean * ad);
#pragma unroll
    for (int i = 0; i < 16; ++i) {
        int p = pt * 16 + i;
        int v = v1[((size_t)n * PP + p) * CC + c];
        u64 m = __ballot(fmaf(a, (float)v, b) > 0.0f);
        if (lane == 0) xp2[((size_t)n * PP + p) * 4 + g] = m;
    }
}

// ---------------------------------------------------------------------------
// finalize: out = clip(SC*(v2 + x) + BI, -1, 1); BN2 inline from f64 stats.
// NHWC int16 -> NCHW f32 via LDS transpose.
// ---------------------------------------------------------------------------
__global__ __launch_bounds__(256) void finalize(const short* __restrict__ v2, const float* __restrict__ x,
                                                const double* __restrict__ s2s, const double* __restrict__ s2q,
                                                const float* __restrict__ gamma, const float* __restrict__ beta,
                                                float* __restrict__ out) {
    __shared__ short t[64 * 66];
    __shared__ float scs[64], bis[64];
    int ct = blockIdx.x, pt = blockIdx.y, n = blockIdx.z;
    int p0 = pt * 64, c0 = ct * 64;
    int tid = threadIdx.x;
    if (tid < 64) {
        int c = c0 + tid;
        double mean = s2s[c] * (1.0 / NHW);
        double msq  = s2q[c] * (1.0 / NHW);
        double var  = msq - mean * mean;
        double istd = 1.0 / sqrt(var + 1e-5);
        double ad   = (double)gamma[c] * istd;
        scs[tid] = (float)ad;
        bis[tid] = (float)((double)beta[c] - mean * ad);
    }
    for (int idx = tid; idx < 64 * 64; idx += 256) {
        int i = idx >> 6, j = idx & 63;
        int p = p0 + i;
        if (p < PP) t[i * 66 + j] = v2[((size_t)n * PP + p) * CC + c0 + j];
    }
    __syncthreads();
    int pl = tid & 63;
    int p = p0 + pl;
    if (p < PP) {
        for (int cl = tid >> 6; cl < 64; cl += 4) {
            int c = c0 + cl;
            float val = (float)t[pl * 66 + cl] + x[((size_t)n * CC + c) * PP + p];
            float r = fmaf(scs[cl], val, bis[cl]);
            r = fminf(fmaxf(r, -1.0f), 1.0f);
            out[((size_t)n * CC + c) * PP + p] = r;
        }
    }
}

// ---------------------------------------------------------------------------
extern "C" void kernel_launch(void* const* d_in, const int* in_sizes, int n_in,
                              void* d_out, int out_size, void* d_ws, size_t ws_size,
                              hipStream_t stream) {
    (void)in_sizes; (void)n_in; (void)out_size; (void)ws_size;
    const float* x   = (const float*)d_in[0];
    const float* w1  = (const float*)d_in[1];
    const float* g1  = (const float*)d_in[2];
    const float* b1  = (const float*)d_in[3];
    const float* w2  = (const float*)d_in[4];
    const float* g2  = (const float*)d_in[5];
    const float* b2  = (const float*)d_in[6];
    float* out = (float*)d_out;

    char* ws = (char*)d_ws;
    u64*    xp1 = (u64*)(ws + 0);            //   802816 B
    u64*    xp2 = (u64*)(ws + 802816);       //   802816 B
    u64*    wp1 = (u64*)(ws + 1605632);      //    73728 B
    u64*    wp2 = (u64*)(ws + 1679360);      //    73728 B
    int*    s1i = (int*)(ws + 1753088);      //     1024 B
    u64*    s1q = (u64*)(ws + 1754112);      //     2048 B
    double* s2s = (double*)(ws + 1756160);   //     2048 B
    double* s2q = (double*)(ws + 1758208);   //     2048 B
    short*  v12 = (short*)(ws + 1764352);    // 12845056 B (v1, then reused as v2)

    prep<<<2176, 64, 0, stream>>>(x, w1, w2, xp1, wp1, wp2, s1i, s1q, s2s, s2q);
    binconv<0><<<dim3(14, 4, 32), 128, 0, stream>>>(xp1, wp1, v12, nullptr, s1i, s1q, nullptr, nullptr);
    repack<<<dim3(49, 32), 256, 0, stream>>>(v12, s1i, s1q, g1, b1, xp2);
    binconv<1><<<dim3(14, 4, 32), 128, 0, stream>>>(xp2, wp2, v12, x, nullptr, nullptr, s2s, s2q);
    finalize<<<dim3(4, 13, 32), 256, 0, stream>>>(v12, x, s2s, s2q, g2, b2, out);
}